// Round 3
// baseline (342.439 us; speedup 1.0000x reference)
//
#include <hip/hip_runtime.h>

#define Ecnt 512
#define Dd 64
#define Aa 8
#define Hh 256
#define Nn 16
#define Tt 128
#define SF2c 0.01f
#define SN2c 0.01f
#define NEGHALF_INV_L2 (-50.0f)   // -0.5 / 0.1^2

// dot of an f32 row (length 4*n4) with an f32 vector in LDS
__device__ __forceinline__ float dotrow(const float* __restrict__ w, const float* v, int n4) {
    const float4* w4 = (const float4*)w;
    float acc = 0.f;
    #pragma unroll 8
    for (int k = 0; k < n4; ++k) {
        float4 q = w4[k];
        acc += q.x * v[4*k+0];
        acc += q.y * v[4*k+1];
        acc += q.z * v[4*k+2];
        acc += q.w * v[4*k+3];
    }
    return acc;
}

// ---------------- k1: per-example GP compute; cov -> ws (once), mu -> out ----
__global__ __launch_bounds__(256, 2) void grp_compute(
    const float* __restrict__ x,
    const float* __restrict__ W1, const float* __restrict__ b1,
    const float* __restrict__ W2, const float* __restrict__ b2,
    const float* __restrict__ Wt, const float* __restrict__ bt,
    const float* __restrict__ Wa, const float* __restrict__ ba,
    const float* __restrict__ tarr,
    float* __restrict__ out_mu, float* __restrict__ ws_cov)
{
    const int e   = blockIdx.x;
    const int tid = threadIdx.x;

    __shared__ float xs[Dd];
    __shared__ float h1[Hh];
    __shared__ float h2[Hh];
    __shared__ float tt[Nn];
    __shared__ float tq[Tt];
    __shared__ float yy[Aa][Nn];
    __shared__ float Km[Nn][Nn + 1];
    __shared__ float Lm[Nn][Nn + 1];
    __shared__ float tmpv[Nn];
    __shared__ __align__(16) float Ks[Tt][Nn];   // Ks[q][i]
    __shared__ __align__(16) float V[Nn][Tt];    // V[i][q] = (K^-1 Ks^T)[i][q]
    __shared__ float alpha[Aa][Nn];

    if (tid < Dd) xs[tid] = x[e * Dd + tid];
    if (tid < Tt) tq[tid] = tarr[tid];
    __syncthreads();

    // MLP
    h1[tid] = tanhf(b1[tid] + dotrow(W1 + tid * Dd, xs, Dd / 4));
    __syncthreads();
    h2[tid] = tanhf(b2[tid] + dotrow(W2 + tid * Hh, h1, Hh / 4));
    __syncthreads();

    // heads
    if (tid < Nn) {
        tt[tid] = bt[tid] + dotrow(Wt + tid * Hh, h2, Hh / 4);
    } else if (tid < Nn + Aa * Nn) {
        int r = tid - Nn;
        float v = ba[r] + dotrow(Wa + r * Hh, h2, Hh / 4);
        yy[r >> 4][r & 15] = v;
    }
    __syncthreads();

    // K and Ks
    {
        int i = tid >> 4, j = tid & 15;
        float d = tt[i] - tt[j];
        Km[i][j] = SF2c * __expf(NEGHALF_INV_L2 * d * d) + (i == j ? SN2c : 0.f);
    }
    #pragma unroll
    for (int r = 0; r < 8; ++r) {
        int idx = tid + r * 256;
        int q = idx >> 4, i = idx & 15;
        float d = tq[q] - tt[i];
        Ks[q][i] = SF2c * __expf(NEGHALF_INV_L2 * d * d);
    }
    __syncthreads();

    // Cholesky
    for (int j = 0; j < Nn; ++j) {
        if (tid >= j && tid < Nn) {
            float s = Km[tid][j];
            for (int k = 0; k < j; ++k) s -= Lm[tid][k] * Lm[j][k];
            tmpv[tid] = s;
        }
        __syncthreads();
        if (tid >= j && tid < Nn) {
            float dj = sqrtf(tmpv[j]);
            Lm[tid][j] = (tid == j) ? dj : tmpv[tid] / dj;
        }
        __syncthreads();
    }

    // batched triangular solves
    if (tid < Tt + Aa) {
        float bz[Nn];
        if (tid < Tt) {
            float tqv = tq[tid];
            #pragma unroll
            for (int i = 0; i < Nn; ++i) {
                float d = tqv - tt[i];
                bz[i] = SF2c * __expf(NEGHALF_INV_L2 * d * d);
            }
        } else {
            int a = tid - Tt;
            #pragma unroll
            for (int i = 0; i < Nn; ++i) bz[i] = yy[a][i];
        }
        #pragma unroll
        for (int i = 0; i < Nn; ++i) {
            float s = bz[i];
            for (int k = 0; k < i; ++k) s -= Lm[i][k] * bz[k];
            bz[i] = s / Lm[i][i];
        }
        #pragma unroll
        for (int i = Nn - 1; i >= 0; --i) {
            float s = bz[i];
            for (int k = i + 1; k < Nn; ++k) s -= Lm[k][i] * bz[k];
            bz[i] = s / Lm[i][i];
        }
        if (tid < Tt) {
            #pragma unroll
            for (int i = 0; i < Nn; ++i) V[i][tid] = bz[i];
        } else {
            int a = tid - Tt;
            #pragma unroll
            for (int i = 0; i < Nn; ++i) alpha[a][i] = bz[i];
        }
    }
    __syncthreads();

    // mu
    if (tid < Tt) {
        float ks[Nn];
        #pragma unroll
        for (int i = 0; i < Nn; ++i) ks[i] = Ks[tid][i];
        size_t mb = (size_t)e * (Aa * Tt) + tid;
        #pragma unroll
        for (int a = 0; a < Aa; ++a) {
            float m = 0.f;
            #pragma unroll
            for (int i = 0; i < Nn; ++i) m += ks[i] * alpha[a][i];
            out_mu[mb + (size_t)a * Tt] = m;
        }
    }

    // cov -> ws, once per example
    {
        const int q4 = (tid & 31) * 4;
        const int pg = tid >> 5;
        float vq[Nn][4];
        #pragma unroll
        for (int i = 0; i < Nn; ++i) {
            float4 vv = *(const float4*)&V[i][q4];
            vq[i][0] = vv.x; vq[i][1] = vv.y; vq[i][2] = vv.z; vq[i][3] = vv.w;
        }
        const float tqq0 = tq[q4 + 0], tqq1 = tq[q4 + 1], tqq2 = tq[q4 + 2], tqq3 = tq[q4 + 3];
        float* covb = ws_cov + (size_t)e * (Tt * Tt);
        #pragma unroll
        for (int pp = 0; pp < 16; ++pp) {
            const int p = pg * 16 + pp;
            float ksp[Nn];
            #pragma unroll
            for (int i4 = 0; i4 < 4; ++i4) {
                float4 kv = *(const float4*)&Ks[p][i4 * 4];
                ksp[i4*4+0] = kv.x; ksp[i4*4+1] = kv.y; ksp[i4*4+2] = kv.z; ksp[i4*4+3] = kv.w;
            }
            const float tqp = tq[p];
            float d0 = tqp - tqq0, d1 = tqp - tqq1, d2 = tqp - tqq2, d3 = tqp - tqq3;
            float a0 = SF2c * __expf(NEGHALF_INV_L2 * d0 * d0);
            float a1 = SF2c * __expf(NEGHALF_INV_L2 * d1 * d1);
            float a2 = SF2c * __expf(NEGHALF_INV_L2 * d2 * d2);
            float a3 = SF2c * __expf(NEGHALF_INV_L2 * d3 * d3);
            #pragma unroll
            for (int i = 0; i < Nn; ++i) {
                a0 -= ksp[i] * vq[i][0];
                a1 -= ksp[i] * vq[i][1];
                a2 -= ksp[i] * vq[i][2];
                a3 -= ksp[i] * vq[i][3];
            }
            float4 pk; pk.x = a0; pk.y = a1; pk.z = a2; pk.w = a3;
            *(float4*)(covb + (size_t)p * Tt + q4) = pk;
        }
    }
}

// ---------------- k2: replicate each example's cov to its 8 anchor slots ----
// block = (e, quarter): reads 32 rows (16 KB, L2/L3-resident), writes 8x16 KB
__global__ __launch_bounds__(256, 4) void grp_replicate(
    const float* __restrict__ ws_cov, float* __restrict__ out_cov)
{
    const int b  = blockIdx.x;
    const int e  = b >> 2;
    const int qr = b & 3;
    const int t  = threadIdx.x;
    const float4* src = (const float4*)(ws_cov + (size_t)e * (Tt * Tt) + qr * (32 * Tt));
    float4* dstb = (float4*)(out_cov + (size_t)e * (Aa * Tt * Tt) + qr * (32 * Tt));
    float4 v0 = src[t + 0 * 256];
    float4 v1 = src[t + 1 * 256];
    float4 v2 = src[t + 2 * 256];
    float4 v3 = src[t + 3 * 256];
    #pragma unroll
    for (int a = 0; a < Aa; ++a) {
        float4* dst = dstb + (size_t)a * (Tt * Tt / 4);
        dst[t + 0 * 256] = v0;
        dst[t + 1 * 256] = v1;
        dst[t + 2 * 256] = v2;
        dst[t + 3 * 256] = v3;
    }
}

extern "C" void kernel_launch(void* const* d_in, const int* in_sizes, int n_in,
                              void* d_out, int out_size, void* d_ws, size_t ws_size,
                              hipStream_t stream) {
    (void)in_sizes; (void)n_in; (void)out_size; (void)ws_size;
    const float* x  = (const float*)d_in[0];
    // d_in[1] (a) and d_in[2] (da) are unused by the reference
    const float* W1 = (const float*)d_in[3];
    const float* b1 = (const float*)d_in[4];
    const float* W2 = (const float*)d_in[5];
    const float* b2 = (const float*)d_in[6];
    const float* Wt = (const float*)d_in[7];
    const float* bt = (const float*)d_in[8];
    const float* Wa = (const float*)d_in[9];
    const float* ba = (const float*)d_in[10];
    const float* ta = (const float*)d_in[11];
    float* mu  = (float*)d_out;
    float* cov = mu + (size_t)Ecnt * Aa * Tt;      // mu first, then cov
    float* wsc = (float*)d_ws;                     // 512 * 128 * 128 * 4B = 32 MB
    grp_compute<<<Ecnt, 256, 0, stream>>>(x, W1, b1, W2, b2, Wt, bt, Wa, ba, ta, mu, wsc);
    grp_replicate<<<Ecnt * 4, 256, 0, stream>>>(wsc, cov);
}

// Round 4
// 307.979 us; speedup vs baseline: 1.1119x; 1.1119x over previous
//
#include <hip/hip_runtime.h>

#define Ecnt 512
#define Dd 64
#define Aa 8
#define Hh 256
#define Nn 16
#define Tt 128
#define NH 144            // Nn + Aa*Nn head outputs (16 times + 128 anchors)
#define SF2c 0.01f
#define SN2c 0.01f
#define NEGHALF_INV_L2 (-50.0f)   // -0.5 / 0.1^2

// ws layout (floats): transposed weights for coalesced MLP loads
#define OFF_W1T 0                          // [Dd][Hh]  W1T[k][o] = W1[o][k]
#define OFF_W2T (OFF_W1T + Dd * Hh)        // [Hh][Hh]  W2T[k][o] = W2[o][k]
#define OFF_WHT (OFF_W2T + Hh * Hh)        // [Hh][NH]  col j<16 -> Wt[j][k], else Wa[j-16][k]
#define OFF_BH  (OFF_WHT + Hh * NH)        // [NH]      bt ++ ba
#define WS_FLOATS (OFF_BH + NH)

__global__ void prep(const float* __restrict__ W1, const float* __restrict__ W2,
                     const float* __restrict__ Wt, const float* __restrict__ Wa,
                     const float* __restrict__ bt, const float* __restrict__ ba,
                     float* __restrict__ ws) {
    int id = blockIdx.x * blockDim.x + threadIdx.x;
    if (id < Dd * Hh) {
        int k = id >> 8, o = id & 255;
        ws[OFF_W1T + id] = W1[o * Dd + k];
    } else if (id < OFF_WHT) {
        int r = id - OFF_W2T; int k = r >> 8, o = r & 255;
        ws[id] = W2[o * Hh + k];
    } else if (id < OFF_BH) {
        int r = id - OFF_WHT; int k = r / NH, j = r % NH;
        ws[id] = (j < Nn) ? Wt[j * Hh + k] : Wa[(j - Nn) * Hh + k];
    } else if (id < WS_FLOATS) {
        int j = id - OFF_BH;
        ws[id] = (j < Nn) ? bt[j] : ba[j - Nn];
    }
}

__global__ __launch_bounds__(256, 2) void grp_fused(
    const float* __restrict__ x,
    const float* __restrict__ b1, const float* __restrict__ b2,
    const float* __restrict__ tarr, const float* __restrict__ ws,
    float* __restrict__ out_mu, float* __restrict__ out_cov)
{
    const int e   = blockIdx.x;
    const int tid = threadIdx.x;

    __shared__ float xs[Dd];
    __shared__ float h1s[Hh];
    __shared__ float h2s[Hh];
    __shared__ float tt[Nn];
    __shared__ float tq[Tt];
    __shared__ float yy[Aa][Nn];
    __shared__ float Km[Nn][Nn + 1];
    __shared__ float Lm[Nn][Nn + 1];
    __shared__ float tmpv[Nn];
    __shared__ __align__(16) float Ks[Tt][Nn];   // Ks[q][i]
    __shared__ __align__(16) float V[Nn][Tt];    // V[i][q]
    __shared__ float alpha[Aa][Nn];

    if (tid < Dd) xs[tid] = x[e * Dd + tid];
    if (tid < Tt) tq[tid] = tarr[tid];
    __syncthreads();

    const float* __restrict__ W1T = ws + OFF_W1T;
    const float* __restrict__ W2T = ws + OFF_W2T;
    const float* __restrict__ WHT = ws + OFF_WHT;
    const float* __restrict__ BH  = ws + OFF_BH;

    // ---- MLP, coalesced: lane = output neuron, k-loop broadcasts activation ----
    {
        float acc = b1[tid];
        #pragma unroll 8
        for (int k = 0; k < Dd; ++k) acc += W1T[k * Hh + tid] * xs[k];
        h1s[tid] = tanhf(acc);
    }
    __syncthreads();
    {
        float acc = b2[tid];
        #pragma unroll 8
        for (int k = 0; k < Hh; ++k) acc += W2T[k * Hh + tid] * h1s[k];
        h2s[tid] = tanhf(acc);
    }
    __syncthreads();
    if (tid < NH) {
        float acc = BH[tid];
        #pragma unroll 8
        for (int k = 0; k < Hh; ++k) acc += WHT[k * NH + tid] * h2s[k];
        if (tid < Nn) tt[tid] = acc;
        else { int r = tid - Nn; yy[r >> 4][r & 15] = acc; }
    }
    __syncthreads();

    // ---- K (16x16, +ridge) and Ks (128x16) ----
    {
        int i = tid >> 4, j = tid & 15;
        float d = tt[i] - tt[j];
        Km[i][j] = SF2c * __expf(NEGHALF_INV_L2 * d * d) + (i == j ? SN2c : 0.f);
    }
    #pragma unroll
    for (int r = 0; r < 8; ++r) {
        int idx = tid + r * 256;
        int q = idx >> 4, i = idx & 15;
        float d = tq[q] - tt[i];
        Ks[q][i] = SF2c * __expf(NEGHALF_INV_L2 * d * d);
    }
    __syncthreads();

    // ---- Cholesky K = L L^T (block-parallel, statically unrolled) ----
    #pragma unroll
    for (int j = 0; j < Nn; ++j) {
        if (tid >= j && tid < Nn) {
            float s = Km[tid][j];
            #pragma unroll
            for (int k = 0; k < j; ++k) s -= Lm[tid][k] * Lm[j][k];
            tmpv[tid] = s;
        }
        __syncthreads();
        if (tid >= j && tid < Nn) {
            float dj = sqrtf(tmpv[j]);
            Lm[tid][j] = (tid == j) ? dj : tmpv[tid] / dj;
        }
        __syncthreads();
    }

    // ---- batched triangular solves: 128 columns of V + 8 alphas ----
    if (tid < Tt + Aa) {
        float bz[Nn];
        if (tid < Tt) {
            float tqv = tq[tid];
            #pragma unroll
            for (int i = 0; i < Nn; ++i) {
                float d = tqv - tt[i];
                bz[i] = SF2c * __expf(NEGHALF_INV_L2 * d * d);
            }
        } else {
            int a = tid - Tt;
            #pragma unroll
            for (int i = 0; i < Nn; ++i) bz[i] = yy[a][i];
        }
        #pragma unroll
        for (int i = 0; i < Nn; ++i) {
            float s = bz[i];
            for (int k = 0; k < i; ++k) s -= Lm[i][k] * bz[k];
            bz[i] = s / Lm[i][i];
        }
        #pragma unroll
        for (int i = Nn - 1; i >= 0; --i) {
            float s = bz[i];
            for (int k = i + 1; k < Nn; ++k) s -= Lm[k][i] * bz[k];
            bz[i] = s / Lm[i][i];
        }
        if (tid < Tt) {
            #pragma unroll
            for (int i = 0; i < Nn; ++i) V[i][tid] = bz[i];
        } else {
            int a = tid - Tt;
            #pragma unroll
            for (int i = 0; i < Nn; ++i) alpha[a][i] = bz[i];
        }
    }
    __syncthreads();

    // ---- mu[a][q] = Ks[q,:] . alpha[a,:] ----
    if (tid < Tt) {
        float ks[Nn];
        #pragma unroll
        for (int i = 0; i < Nn; ++i) ks[i] = Ks[tid][i];
        size_t mb = (size_t)e * (Aa * Tt) + tid;
        #pragma unroll
        for (int a = 0; a < Aa; ++a) {
            float m = 0.f;
            #pragma unroll
            for (int i = 0; i < Nn; ++i) m += ks[i] * alpha[a][i];
            out_mu[mb + (size_t)a * Tt] = m;
        }
    }

    // ---- cov[p][q] = Kss[p][q] - Ks[p,:].V[:,q]; identical for all 8 anchors ----
    {
        const int q4 = (tid & 31) * 4;
        const int pg = tid >> 5;
        float vq[Nn][4];
        #pragma unroll
        for (int i = 0; i < Nn; ++i) {
            float4 vv = *(const float4*)&V[i][q4];
            vq[i][0] = vv.x; vq[i][1] = vv.y; vq[i][2] = vv.z; vq[i][3] = vv.w;
        }
        const float tqq0 = tq[q4 + 0], tqq1 = tq[q4 + 1], tqq2 = tq[q4 + 2], tqq3 = tq[q4 + 3];
        float* covb = out_cov + (size_t)e * (Aa * Tt * Tt);
        #pragma unroll
        for (int pp = 0; pp < 16; ++pp) {
            const int p = pg * 16 + pp;
            float ksp[Nn];
            #pragma unroll
            for (int i4 = 0; i4 < 4; ++i4) {
                float4 kv = *(const float4*)&Ks[p][i4 * 4];
                ksp[i4*4+0] = kv.x; ksp[i4*4+1] = kv.y; ksp[i4*4+2] = kv.z; ksp[i4*4+3] = kv.w;
            }
            const float tqp = tq[p];
            float d0 = tqp - tqq0, d1 = tqp - tqq1, d2 = tqp - tqq2, d3 = tqp - tqq3;
            float a0 = SF2c * __expf(NEGHALF_INV_L2 * d0 * d0);
            float a1 = SF2c * __expf(NEGHALF_INV_L2 * d1 * d1);
            float a2 = SF2c * __expf(NEGHALF_INV_L2 * d2 * d2);
            float a3 = SF2c * __expf(NEGHALF_INV_L2 * d3 * d3);
            #pragma unroll
            for (int i = 0; i < Nn; ++i) {
                a0 -= ksp[i] * vq[i][0];
                a1 -= ksp[i] * vq[i][1];
                a2 -= ksp[i] * vq[i][2];
                a3 -= ksp[i] * vq[i][3];
            }
            float4 pk; pk.x = a0; pk.y = a1; pk.z = a2; pk.w = a3;
            const size_t ro = (size_t)p * Tt + q4;
            #pragma unroll
            for (int a = 0; a < Aa; ++a) {
                *(float4*)(covb + (size_t)a * (Tt * Tt) + ro) = pk;
            }
        }
    }
}

extern "C" void kernel_launch(void* const* d_in, const int* in_sizes, int n_in,
                              void* d_out, int out_size, void* d_ws, size_t ws_size,
                              hipStream_t stream) {
    (void)in_sizes; (void)n_in; (void)out_size; (void)ws_size;
    const float* x  = (const float*)d_in[0];
    // d_in[1] (a) and d_in[2] (da) are unused by the reference
    const float* W1 = (const float*)d_in[3];
    const float* b1 = (const float*)d_in[4];
    const float* W2 = (const float*)d_in[5];
    const float* b2 = (const float*)d_in[6];
    const float* Wt = (const float*)d_in[7];
    const float* bt = (const float*)d_in[8];
    const float* Wa = (const float*)d_in[9];
    const float* ba = (const float*)d_in[10];
    const float* ta = (const float*)d_in[11];
    float* mu  = (float*)d_out;
    float* cov = mu + (size_t)Ecnt * Aa * Tt;      // mu first, then cov
    float* wsf = (float*)d_ws;

    prep<<<(WS_FLOATS + 255) / 256, 256, 0, stream>>>(W1, W2, Wt, Wa, bt, ba, wsf);
    grp_fused<<<Ecnt, 256, 0, stream>>>(x, b1, b2, ta, wsf, mu, cov);
}